// Round 10
// baseline (426.566 us; speedup 1.0000x reference)
//
#include <hip/hip_runtime.h>

#define TT 2048
#define NV 1000
#define LOG2E 1.4426950408889634f

typedef float f32x2 __attribute__((ext_vector_type(2)));

// ---- XLA/Eigen rational tanh — epilogue head only (off critical path).
__device__ __forceinline__ float tanh_fast(float x) {
    const float L = 7.90531110763549805f;
    x = __builtin_amdgcn_fmed3f(x, -L, L);
    float x2 = x * x;
    float p = -2.76076847742355e-16f;
    p = __builtin_fmaf(p, x2, 2.00018790482477e-13f);
    p = __builtin_fmaf(p, x2, -8.60467152213735e-11f);
    p = __builtin_fmaf(p, x2, 5.12229709037114e-08f);
    p = __builtin_fmaf(p, x2, 1.48572235717979e-05f);
    p = __builtin_fmaf(p, x2, 6.37261928875436e-04f);
    p = __builtin_fmaf(p, x2, 4.89352455891786e-03f);
    float q = 1.19825839466702e-06f;
    q = __builtin_fmaf(q, x2, 1.18534705686654e-04f);
    q = __builtin_fmaf(q, x2, 2.26843463243900e-03f);
    q = __builtin_fmaf(q, x2, 4.89352518554385e-03f);
    float r = __builtin_amdgcn_rcpf(q);
    return (x * p) * r;
}

// DPP cross-lane.
template <int CTRL>
__device__ __forceinline__ float dppf(float x) {
    return __int_as_float(__builtin_amdgcn_update_dpp(
        0, __float_as_int(x), CTRL, 0xF, 0xF, true));
}
#define DPP_XOR1 0xB1   // quad_perm [1,0,3,2]
#define DPP_XOR2 0x4E   // quad_perm [2,3,0,1]
#define DPP_XOR3 0x1B   // quad_perm [3,2,1,0]
#define DPP_ROR4 0x124  // row_ror:4 == xor4 on period-8 data (validated R3-R10)
#define DPP_HMIR 0x141  // row_half_mirror == xor7 within 8-lane half
#define DPP_ROR8 0x128  // row_ror:8 == xor8 within 16-row

// pk helpers: per-component ops are bitwise-identical to the scalar forms.
__device__ __forceinline__ f32x2 pkfma(f32x2 a, float b, f32x2 c) {
    return __builtin_elementwise_fma(a, (f32x2){b, b}, c);
}

// R19: TWO INDEPENDENT RECURRENCES PER WAVE (ILP, not TLP).
// Locked model (R12/R14/R17/R18): per-SIMD step time = max(serial chain
// ~258 cyc, sum of per-wave busy ~172 cyc). Multi-wave (R12/R17) loses
// because a 2nd wave duplicates per-wave fixed costs. A 2nd CHAIN in the
// SAME wave shares weights + instruction stream: per step-pair issue
// ~2x172=344, chains' stall windows fill each other -> ~172 cyc/step.
// Each 16-lane group carries rows b and b+16 (states A and B), STEP_AB
// manually interleaves the two R14-verbatim step bodies. Grid 128 x 256
// (32 rows/block, 1 block/CU; half the chip idle - irrelevant, per-wave
// bound). Per-row arithmetic is R14 VERBATIM (absmax-0.0 validated):
//   lo slot: s=0 sigma(i)=r; s=1 k*tanh(g)=fma(2k,r,-k), k=-2log2e
//   hi slot: sigma via rcp(1+exp2(-log2e*pre))
//   cs = fma(F, cs, IG) [scaled domain]; ec=exp2(cs); hn=fma(2O,rc,-O)
extern "C" __global__ void __launch_bounds__(256, 1)
lstm_fused(const int* __restrict__ x, const float* __restrict__ emb,
           const float* __restrict__ W_ih, const float* __restrict__ W_hh,
           const float* __restrict__ b_ih, const float* __restrict__ b_hh,
           const float* __restrict__ W_cls, const float* __restrict__ b_cls,
           float* __restrict__ out)
{
    extern __shared__ float TAB[];  // [1000][16] float2 rows, stride 128 B

    const int tid = threadIdx.x;
    const int l   = tid & 15;
    const int s   = l >> 3;
    const int j   = l & 7;
    const int grp = tid >> 4;

    const int glo = j + (s << 4);          // i_j (s0) or g_j (s1)
    const int ghi = glo + 8;               // f_j (s0) or o_j (s1)
    const float scx = s ? (-2.0f * LOG2E) : -LOG2E;  // lo-slot prescale
    const float scy = -LOG2E;                        // hi-slot sigma prescale
    // aLk = fma(Ax, r, Bx):  s0 -> sigma(i) = r (fma(1,r,0), exact)
    //                        s1 -> k*tanh(g) = fma(2k, r, -k), k = -2log2e
    const float Ax = s ? (-4.0f * LOG2E) : 1.0f;
    const float Bx = s ? ( 2.0f * LOG2E) : 0.0f;
    const bool is0 = (s == 0);

    // ---- phase 1: build TAB ----
    {
        float wl[8], wh[8];
        #pragma unroll
        for (int k = 0; k < 8; ++k) {
            wl[k] = W_ih[glo * 8 + k];
            wh[k] = W_ih[ghi * 8 + k];
        }
        const float bl = b_ih[glo] + b_hh[glo];
        const float bh = b_ih[ghi] + b_hh[ghi];
        for (int v = grp; v < NV; v += 16) {
            const float4 e0 = *(const float4*)(emb + v * 8);
            const float4 e1 = *(const float4*)(emb + v * 8 + 4);
            float dl = bl + e0.x*wl[0] + e0.y*wl[1] + e0.z*wl[2] + e0.w*wl[3]
                          + e1.x*wl[4] + e1.y*wl[5] + e1.z*wl[6] + e1.w*wl[7];
            float dh = bh + e0.x*wh[0] + e0.y*wh[1] + e0.z*wh[2] + e0.w*wh[3]
                          + e1.x*wh[4] + e1.y*wh[5] + e1.z*wh[6] + e1.w*wh[7];
            *(float2*)(TAB + v * 32 + l * 2) = make_float2(scx * dl, scy * dh);
        }
    }
    __syncthreads();

    // ---- recurrence: rows bA (chain A) and bB = bA+16 (chain B) ----
    const int bA = blockIdx.x * 32 + grp;
    const int bB = bA + 16;
    const int* __restrict__ xrowA = x + (size_t)bA * TT;
    const int* __restrict__ xrowB = x + (size_t)bB * TT;
    const char* __restrict__ TABl = (const char*)TAB + l * 8;  // lane base

    // xor-ordered W_hh packed {lo,hi} — SHARED by both chains.
    f32x2 wpk[8];
    #pragma unroll
    for (int m = 0; m < 8; ++m) {
        wpk[m].x = scx * W_hh[glo * 8 + (j ^ m)];
        wpk[m].y = scy * W_hh[ghi * 8 + (j ^ m)];
    }

    float csA = 0.0f, hnA = 0.0f;
    float csB = 0.0f, hnB = 0.0f;

    int4 iAa = *(const int4*)(xrowA);
    int4 iBa = *(const int4*)(xrowA + 4);
    int4 iAb = *(const int4*)(xrowB);
    int4 iBb = *(const int4*)(xrowB + 4);
    f32x2 xg0a = *(const f32x2*)(TABl + (iAa.x << 7));  // depth-2 prefetch
    f32x2 xg1a = *(const f32x2*)(TABl + (iAa.y << 7));
    f32x2 xg0b = *(const f32x2*)(TABl + (iAb.x << 7));
    f32x2 xg1b = *(const f32x2*)(TABl + (iAb.y << 7));

    // Two R14-verbatim step bodies, manually interleaved A/B so the in-order
    // wave never issues back-to-back dependent instructions.
#define STEP_AB(XGa, XGb, NIa, NIb) do {                                         \
        float mmA = dppf<DPP_HMIR>(hnA);                                         \
        float mmB = dppf<DPP_HMIR>(hnB);                                         \
        f32x2 uAa = pkfma(wpk[0], hnA, XGa);                                     \
        f32x2 uAb = pkfma(wpk[0], hnB, XGb);                                     \
        float h1a = dppf<DPP_XOR1>(hnA);                                         \
        float h1b = dppf<DPP_XOR1>(hnB);                                         \
        f32x2 uBa = wpk[1] * (f32x2){h1a, h1a};                                  \
        f32x2 uBb = wpk[1] * (f32x2){h1b, h1b};                                  \
        uAa = pkfma(wpk[2], dppf<DPP_XOR2>(hnA), uAa);                           \
        uAb = pkfma(wpk[2], dppf<DPP_XOR2>(hnB), uAb);                           \
        uBa = pkfma(wpk[3], dppf<DPP_XOR3>(hnA), uBa);                           \
        uBb = pkfma(wpk[3], dppf<DPP_XOR3>(hnB), uBb);                           \
        uAa = pkfma(wpk[4], dppf<DPP_XOR3>(mmA), uAa);                           \
        uAb = pkfma(wpk[4], dppf<DPP_XOR3>(mmB), uAb);                           \
        uBa = pkfma(wpk[5], dppf<DPP_XOR2>(mmA), uBa);                           \
        uBb = pkfma(wpk[5], dppf<DPP_XOR2>(mmB), uBb);                           \
        uAa = pkfma(wpk[6], dppf<DPP_XOR1>(mmA), uAa);                           \
        uAb = pkfma(wpk[6], dppf<DPP_XOR1>(mmB), uAb);                           \
        uBa = pkfma(wpk[7], mmA, uBa);                                           \
        uBb = pkfma(wpk[7], mmB, uBb);                                           \
        f32x2 ua = uAa + uBa;                                                    \
        f32x2 ub = uAb + uBb;                                                    \
        XGa = *(const f32x2*)(TABl + ((NIa) << 7));   /* prefetch t+2 */         \
        XGb = *(const f32x2*)(TABl + ((NIb) << 7));                              \
        float elA = __builtin_amdgcn_exp2f(ua.x);                                \
        float elB = __builtin_amdgcn_exp2f(ub.x);                                \
        float eyA = __builtin_amdgcn_exp2f(ua.y);                                \
        float eyB = __builtin_amdgcn_exp2f(ub.y);                                \
        float rA  = __builtin_amdgcn_rcpf(1.0f + elA);                           \
        float rB  = __builtin_amdgcn_rcpf(1.0f + elB);                           \
        float aLkA = __builtin_fmaf(Ax, rA, Bx);                                 \
        float aLkB = __builtin_fmaf(Ax, rB, Bx);                                 \
        float syA = __builtin_amdgcn_rcpf(1.0f + eyA);                           \
        float syB = __builtin_amdgcn_rcpf(1.0f + eyB);                           \
        float IGA = dppf<DPP_ROR8>(aLkA) * aLkA;                                 \
        float IGB = dppf<DPP_ROR8>(aLkB) * aLkB;                                 \
        float pHiA = dppf<DPP_ROR8>(syA);                                        \
        float pHiB = dppf<DPP_ROR8>(syB);                                        \
        float FA = is0 ? syA : pHiA;                                             \
        float FB = is0 ? syB : pHiB;                                             \
        float OA = is0 ? pHiA : syA;                                             \
        float OB = is0 ? pHiB : syB;                                             \
        float twoOA = OA + OA;                                                   \
        float twoOB = OB + OB;                                                   \
        csA = __builtin_fmaf(FA, csA, IGA);                                      \
        csB = __builtin_fmaf(FB, csB, IGB);                                      \
        float ecA = __builtin_amdgcn_exp2f(csA);                                 \
        float ecB = __builtin_amdgcn_exp2f(csB);                                 \
        float rcA = __builtin_amdgcn_rcpf(1.0f + ecA);                           \
        float rcB = __builtin_amdgcn_rcpf(1.0f + ecB);                           \
        hnA = __builtin_fmaf(twoOA, rcA, -OA);                                   \
        hnB = __builtin_fmaf(twoOB, rcB, -OB);                                   \
    } while (0)

    for (int t = 0; t < TT; t += 4) {
        const int nb = (t + 8 < TT) ? (t / 4 + 2) : 0;  // clamp tail prefetch
        int4 iNa = *(const int4*)(xrowA + nb * 4);
        int4 iNb = *(const int4*)(xrowB + nb * 4);
        STEP_AB(xg0a, xg0b, iAa.z, iAb.z);
        STEP_AB(xg1a, xg1b, iAa.w, iAb.w);
        STEP_AB(xg0a, xg0b, iBa.x, iBb.x);
        STEP_AB(xg1a, xg1b, iBa.y, iBb.y);
        iAa = iBa; iBa = iNa;
        iAb = iBb; iBb = iNb;
    }
#undef STEP_AB

    // ---- head: out[b] = 0.5 + 0.5*tanh(0.5*(h.W_cls + b_cls)) ----
    // Lane l==0: hn=h_0, v_m=h_m -> same summation order as R2-R18. Twice.
    {
        float v1 = dppf<DPP_XOR1>(hnA);
        float v2 = dppf<DPP_XOR2>(hnA);
        float v3 = dppf<DPP_XOR3>(hnA);
        float v4 = dppf<DPP_ROR4>(hnA);
        float v5 = dppf<DPP_XOR1>(v4);
        float v6 = dppf<DPP_XOR2>(v4);
        float v7 = dppf<DPP_XOR3>(v4);
        float w1 = dppf<DPP_XOR1>(hnB);
        float w2 = dppf<DPP_XOR2>(hnB);
        float w3 = dppf<DPP_XOR3>(hnB);
        float w4 = dppf<DPP_ROR4>(hnB);
        float w5 = dppf<DPP_XOR1>(w4);
        float w6 = dppf<DPP_XOR2>(w4);
        float w7 = dppf<DPP_XOR3>(w4);
        if (l == 0) {
            float zA = b_cls[0]
                + hnA * W_cls[0] + v1 * W_cls[1] + v2 * W_cls[2] + v3 * W_cls[3]
                + v4 * W_cls[4] + v5 * W_cls[5] + v6 * W_cls[6] + v7 * W_cls[7];
            out[bA] = __builtin_fmaf(0.5f, tanh_fast(0.5f * zA), 0.5f);
            float zB = b_cls[0]
                + hnB * W_cls[0] + w1 * W_cls[1] + w2 * W_cls[2] + w3 * W_cls[3]
                + w4 * W_cls[4] + w5 * W_cls[5] + w6 * W_cls[6] + w7 * W_cls[7];
            out[bB] = __builtin_fmaf(0.5f, tanh_fast(0.5f * zB), 0.5f);
        }
    }
}

extern "C" void kernel_launch(void* const* d_in, const int* in_sizes, int n_in,
                              void* d_out, int out_size, void* d_ws, size_t ws_size,
                              hipStream_t stream)
{
    (void)in_sizes; (void)n_in; (void)d_ws; (void)ws_size; (void)out_size;
    const int*   x     = (const int*)  d_in[0];
    const float* emb   = (const float*)d_in[1];
    const float* W_ih  = (const float*)d_in[2];
    const float* W_hh  = (const float*)d_in[3];
    const float* b_ih  = (const float*)d_in[4];
    const float* b_hh  = (const float*)d_in[5];
    const float* W_cls = (const float*)d_in[6];
    const float* b_cls = (const float*)d_in[7];
    float* out = (float*)d_out;

    const int lds_bytes = NV * 16 * 8;  // 128000 <= 163840 (gfx950 opt-in)
    hipFuncSetAttribute((const void*)lstm_fused,
                        hipFuncAttributeMaxDynamicSharedMemorySize, lds_bytes);

    lstm_fused<<<dim3(128), dim3(256), lds_bytes, stream>>>(
        x, emb, W_ih, W_hh, b_ih, b_hh, W_cls, b_cls, out);
}

// Round 11
// 273.676 us; speedup vs baseline: 1.5587x; 1.5587x over previous
//
#include <hip/hip_runtime.h>

#define TT 2048
#define NV 1000
#define LOG2E 1.4426950408889634f

typedef float f32x2 __attribute__((ext_vector_type(2)));

// ---- XLA/Eigen rational tanh — epilogue head only (off critical path).
__device__ __forceinline__ float tanh_fast(float x) {
    const float L = 7.90531110763549805f;
    x = __builtin_amdgcn_fmed3f(x, -L, L);
    float x2 = x * x;
    float p = -2.76076847742355e-16f;
    p = __builtin_fmaf(p, x2, 2.00018790482477e-13f);
    p = __builtin_fmaf(p, x2, -8.60467152213735e-11f);
    p = __builtin_fmaf(p, x2, 5.12229709037114e-08f);
    p = __builtin_fmaf(p, x2, 1.48572235717979e-05f);
    p = __builtin_fmaf(p, x2, 6.37261928875436e-04f);
    p = __builtin_fmaf(p, x2, 4.89352455891786e-03f);
    float q = 1.19825839466702e-06f;
    q = __builtin_fmaf(q, x2, 1.18534705686654e-04f);
    q = __builtin_fmaf(q, x2, 2.26843463243900e-03f);
    q = __builtin_fmaf(q, x2, 4.89352518554385e-03f);
    float r = __builtin_amdgcn_rcpf(q);
    return (x * p) * r;
}

// DPP cross-lane.
template <int CTRL>
__device__ __forceinline__ float dppf(float x) {
    return __int_as_float(__builtin_amdgcn_update_dpp(
        0, __float_as_int(x), CTRL, 0xF, 0xF, true));
}
#define DPP_XOR1 0xB1   // quad_perm [1,0,3,2]
#define DPP_XOR2 0x4E   // quad_perm [2,3,0,1]
#define DPP_XOR3 0x1B   // quad_perm [3,2,1,0]
#define DPP_ROR4 0x124  // row_ror:4 == xor4 on period-8 data (validated R3-R10)
#define DPP_HMIR 0x141  // row_half_mirror == xor7 within 8-lane half
#define DPP_ROR8 0x128  // row_ror:8 == xor8 within 16-row

// pk helpers: per-component ops are bitwise-identical to the scalar forms.
__device__ __forceinline__ f32x2 pkfma(f32x2 a, float b, f32x2 c) {
    return __builtin_elementwise_fma(a, (f32x2){b, b}, c);
}

// R20 = R14 verbatim (verified best: 220.4 us, absmax 0.0, Round 4).
// Converged model (R12-R19): wall = 2048 x T_iter; T_iter = ~172 issue
// (52 VALU x 2cyc + 6 trans) + ~86 dependent-latency through the serial
// chain. All structural alternatives bracket this as the basin floor:
// +instr costs ~3 cyc/instr (R15/R16), occupancy/ILP packing cannot
// shorten the 2048-step critical path (R12/R17/R19), coarser lane
// layouts raise per-lane work (R18). 16-lane lo/hi gate pairing
// amortizes per-wave trans/glue over 4 rows — the max this op allows.
//  (1) tanh via fma(2,r,-1) form (no clamps; rcp(inf)=0 -> +/-1 exact).
//  (2) c in scaled domain cs = -2log2e*c; scale folded into tanh(g)
//      fma constants -> exp2(cs) direct on the chain.
//  (3) hn = fma(2O, rc, -O), 2O computed off-chain.
extern "C" __global__ void __launch_bounds__(256, 1)
lstm_fused(const int* __restrict__ x, const float* __restrict__ emb,
           const float* __restrict__ W_ih, const float* __restrict__ W_hh,
           const float* __restrict__ b_ih, const float* __restrict__ b_hh,
           const float* __restrict__ W_cls, const float* __restrict__ b_cls,
           float* __restrict__ out)
{
    extern __shared__ float TAB[];  // [1000][16] float2 rows, stride 128 B

    const int tid = threadIdx.x;
    const int l   = tid & 15;
    const int s   = l >> 3;
    const int j   = l & 7;
    const int grp = tid >> 4;

    const int glo = j + (s << 4);          // i_j (s0) or g_j (s1)
    const int ghi = glo + 8;               // f_j (s0) or o_j (s1)
    const float scx = s ? (-2.0f * LOG2E) : -LOG2E;  // lo-slot prescale
    const float scy = -LOG2E;                        // hi-slot sigma prescale
    // aLk = fma(Ax, r, Bx):  s0 -> sigma(i) = r (fma(1,r,0), exact)
    //                        s1 -> k*tanh(g) = fma(2k, r, -k), k = -2log2e
    const float Ax = s ? (-4.0f * LOG2E) : 1.0f;
    const float Bx = s ? ( 2.0f * LOG2E) : 0.0f;
    const bool is0 = (s == 0);

    // ---- phase 1: build TAB ----
    {
        float wl[8], wh[8];
        #pragma unroll
        for (int k = 0; k < 8; ++k) {
            wl[k] = W_ih[glo * 8 + k];
            wh[k] = W_ih[ghi * 8 + k];
        }
        const float bl = b_ih[glo] + b_hh[glo];
        const float bh = b_ih[ghi] + b_hh[ghi];
        for (int v = grp; v < NV; v += 16) {
            const float4 e0 = *(const float4*)(emb + v * 8);
            const float4 e1 = *(const float4*)(emb + v * 8 + 4);
            float dl = bl + e0.x*wl[0] + e0.y*wl[1] + e0.z*wl[2] + e0.w*wl[3]
                          + e1.x*wl[4] + e1.y*wl[5] + e1.z*wl[6] + e1.w*wl[7];
            float dh = bh + e0.x*wh[0] + e0.y*wh[1] + e0.z*wh[2] + e0.w*wh[3]
                          + e1.x*wh[4] + e1.y*wh[5] + e1.z*wh[6] + e1.w*wh[7];
            *(float2*)(TAB + v * 32 + l * 2) = make_float2(scx * dl, scy * dh);
        }
    }
    __syncthreads();

    // ---- recurrence ----
    const int b = blockIdx.x * 16 + grp;
    const int* __restrict__ xrow = x + (size_t)b * TT;
    const char* __restrict__ TABl = (const char*)TAB + l * 8;  // lane base

    // xor-ordered W_hh packed {lo,hi} (pairs with m_k = h_{j^m}; R3-R19 exact)
    f32x2 wpk[8];
    #pragma unroll
    for (int m = 0; m < 8; ++m) {
        wpk[m].x = scx * W_hh[glo * 8 + (j ^ m)];
        wpk[m].y = scy * W_hh[ghi * 8 + (j ^ m)];
    }

    float cs = 0.0f;   // scaled cell state: cs = -2log2e * c
    float hn = 0.0f;   // lane l: h_{l&7} (period-8 within 16-row)

    int4 iA = *(const int4*)(xrow);
    int4 iB = *(const int4*)(xrow + 4);
    f32x2 xg0 = *(const f32x2*)(TABl + (iA.x << 7));  // depth-2 prefetch
    f32x2 xg1 = *(const f32x2*)(TABl + (iA.y << 7));

    // Dot chain order per component == R6/R9/R13: uA: m0,m2,m4,m6; uB: m1..m7.
#define STEP(XG, NIDX) do {                                                      \
        float mm  = dppf<DPP_HMIR>(hn);          /* m7, multi-use */             \
        f32x2 uA = pkfma(wpk[0], hn, XG);                                        \
        f32x2 uB = wpk[1] * (f32x2){dppf<DPP_XOR1>(hn), dppf<DPP_XOR1>(hn)};     \
        uA = pkfma(wpk[2], dppf<DPP_XOR2>(hn), uA);                              \
        uB = pkfma(wpk[3], dppf<DPP_XOR3>(hn), uB);                              \
        uA = pkfma(wpk[4], dppf<DPP_XOR3>(mm), uA);                              \
        uB = pkfma(wpk[5], dppf<DPP_XOR2>(mm), uB);                              \
        uA = pkfma(wpk[6], dppf<DPP_XOR1>(mm), uA);                              \
        uB = pkfma(wpk[7], mm, uB);                                              \
        f32x2 u = uA + uB;  /* .x: s0 -log2e*pre_i / s1 -2log2e*pre_g */         \
        XG = *(const f32x2*)(TABl + ((NIDX) << 7));   /* prefetch t+2 */         \
        float el = __builtin_amdgcn_exp2f(u.x);                                  \
        float ey = __builtin_amdgcn_exp2f(u.y);                                  \
        float r  = __builtin_amdgcn_rcpf(1.0f + el);                             \
        float aLk = __builtin_fmaf(Ax, r, Bx);   /* sig(i) / k*tanh(g) */        \
        float sy = __builtin_amdgcn_rcpf(1.0f + ey);  /* sig(f)/sig(o) */        \
        float IG  = dppf<DPP_ROR8>(aLk) * aLk;   /* k*sig(i)*tanh(g), both */    \
        float pHi = dppf<DPP_ROR8>(sy);                                          \
        float F   = is0 ? sy : pHi;     /* sig(f) */                             \
        float O   = is0 ? pHi : sy;     /* sig(o) */                             \
        float twoO = O + O;                                                      \
        cs = __builtin_fmaf(F, cs, IG);          /* cs = k*c */                  \
        float ec = __builtin_amdgcn_exp2f(cs);   /* e^{-2c}, inf-safe */         \
        float rc = __builtin_amdgcn_rcpf(1.0f + ec);                             \
        hn = __builtin_fmaf(twoO, rc, -O);       /* O * tanh(c) */               \
    } while (0)

    for (int t = 0; t < TT; t += 4) {
        const int nb = (t + 8 < TT) ? (t / 4 + 2) : 0;  // clamp tail prefetch
        int4 iN = *(const int4*)(xrow + nb * 4);
        STEP(xg0, iA.z);
        STEP(xg1, iA.w);
        STEP(xg0, iB.x);
        STEP(xg1, iB.y);
        iA = iB; iB = iN;
    }
#undef STEP

    // ---- head: out[b] = 0.5 + 0.5*tanh(0.5*(h.W_cls + b_cls)) ----
    // Lane l==0: hn=h_0, v_m=h_m -> same summation order as R2-R19.
    {
        float v1 = dppf<DPP_XOR1>(hn);
        float v2 = dppf<DPP_XOR2>(hn);
        float v3 = dppf<DPP_XOR3>(hn);
        float v4 = dppf<DPP_ROR4>(hn);
        float v5 = dppf<DPP_XOR1>(v4);
        float v6 = dppf<DPP_XOR2>(v4);
        float v7 = dppf<DPP_XOR3>(v4);
        if (l == 0) {
            float z = b_cls[0]
                + hn * W_cls[0] + v1 * W_cls[1] + v2 * W_cls[2] + v3 * W_cls[3]
                + v4 * W_cls[4] + v5 * W_cls[5] + v6 * W_cls[6] + v7 * W_cls[7];
            out[b] = __builtin_fmaf(0.5f, tanh_fast(0.5f * z), 0.5f);
        }
    }
}

extern "C" void kernel_launch(void* const* d_in, const int* in_sizes, int n_in,
                              void* d_out, int out_size, void* d_ws, size_t ws_size,
                              hipStream_t stream)
{
    (void)in_sizes; (void)n_in; (void)d_ws; (void)ws_size; (void)out_size;
    const int*   x     = (const int*)  d_in[0];
    const float* emb   = (const float*)d_in[1];
    const float* W_ih  = (const float*)d_in[2];
    const float* W_hh  = (const float*)d_in[3];
    const float* b_ih  = (const float*)d_in[4];
    const float* b_hh  = (const float*)d_in[5];
    const float* W_cls = (const float*)d_in[6];
    const float* b_cls = (const float*)d_in[7];
    float* out = (float*)d_out;

    const int lds_bytes = NV * 16 * 8;  // 128000 <= 163840 (gfx950 opt-in)
    hipFuncSetAttribute((const void*)lstm_fused,
                        hipFuncAttributeMaxDynamicSharedMemorySize, lds_bytes);

    lstm_fused<<<dim3(256), dim3(256), lds_bytes, stream>>>(
        x, emb, W_ih, W_hh, b_ih, b_hh, W_cls, b_cls, out);
}